// Round 1
// baseline (15329.951 us; speedup 1.0000x reference)
//
#include <hip/hip_runtime.h>

// LSTM: B=128, T=1024, D=512, H=512, gates 4H=2048.
// in: x (B,T,D) f32 | Wx (512,2048) f32 | Wh (512,2048) f32 | b (2048) f32
// out: final h (128,512) f32
//
// Plan:
//  prep:    Wx,Wh -> f16 transposed [2048][512] in ws; zero h/c/barrier counters
//  gemm_xg: xg[b*Tc+t][g] = x@Wx + b  (f16 out, chunked over T by ws_size)
//  lstm_rec: persistent coop kernel, 8 groups (16 batches) x 16 hidden-slice wgs,
//            Wh slice in registers, group-local atomic barrier per step.

typedef _Float16 f16;
typedef _Float16 f16x2 __attribute__((ext_vector_type(2)));
typedef _Float16 f16x8 __attribute__((ext_vector_type(8)));
typedef float f32x4 __attribute__((ext_vector_type(4)));

#define MFMA16(a, b, c) __builtin_amdgcn_mfma_f32_16x16x32_f16(a, b, c, 0, 0, 0)

__device__ __forceinline__ float sigf(float x) { return 1.0f / (1.0f + __expf(-x)); }
__device__ __forceinline__ float tanh_fast(float x) { return 1.0f - 2.0f / (__expf(2.0f * x) + 1.0f); }

// ---------------------------------------------------------------- prep
__global__ __launch_bounds__(256) void prep_kernel(
    const float* __restrict__ Wx, const float* __restrict__ Wh,
    f16* __restrict__ wxT, f16* __restrict__ whT,
    f16* __restrict__ hbuf, float* __restrict__ cst, unsigned* __restrict__ cnt)
{
    unsigned i = blockIdx.x * 256u + threadIdx.x;
    if (i < 1048576u) {                    // 2048*512 transpose, W[d][g] -> WT[g][d]
        unsigned g = i >> 9, d = i & 511u;
        wxT[i] = (f16)Wx[d * 2048u + g];
        whT[i] = (f16)Wh[d * 2048u + g];
    }
    if (i < 65536u) {                      // zero both h double-buffers (2*128*512 f16)
        ((unsigned*)hbuf)[i] = 0u;
        cst[i] = 0.0f;                     // zero c state (128*512 f32)
    }
    if (i < 512u) cnt[i] = 0u;             // barrier counters (8 groups, padded)
}

// ---------------------------------------------------------------- xg GEMM
// M = 128*Tc (row = b*Tc + t_local), N = 2048, K = 512. 128x128 tile, 4 waves.
__global__ __launch_bounds__(256) void gemm_xg(
    const float* __restrict__ x, const f16* __restrict__ wxT,
    const float* __restrict__ bias, f16* __restrict__ xg,
    int t0, int tcLog)
{
    __shared__ f16 smem[16384];            // 32 KB: A[128][32] | B[128][32], reused as Os[128][128]
    f16* As = smem;
    f16* Bs = smem + 4096;

    const int tid = threadIdx.x;
    const int lane = tid & 63, wid = tid >> 6;
    const int wm = wid >> 1, wn = wid & 1;
    const int lr = lane & 15, lh = lane >> 4;
    const int n0 = blockIdx.x * 128;
    const long m0 = (long)blockIdx.y * 128;

    // staging: thread -> (row, 2 chunks of 8 f16)
    const int srow = tid >> 1;
    const int sc0 = (tid & 1) * 2;
    const int swz = (srow >> 1) & 3;

    const long mg = m0 + srow;
    const long bb = mg >> tcLog;
    const long tl = mg & ((1L << tcLog) - 1);
    const float* xrow = x + ((bb * 1024 + t0 + tl) * 512 + sc0 * 8);
    const f16* brow = wxT + ((long)(n0 + srow) * 512 + sc0 * 8);

    f32x4 acc[4][4] = {};

    for (int k0 = 0; k0 < 512; k0 += 32) {
        __syncthreads();
        // stage A (fp32 -> f16 in regs)
        float4 a0 = *(const float4*)(xrow + k0);
        float4 a1 = *(const float4*)(xrow + k0 + 4);
        float4 a2 = *(const float4*)(xrow + k0 + 8);
        float4 a3 = *(const float4*)(xrow + k0 + 12);
        f16x8 ha, hb;
        ha[0] = (f16)a0.x; ha[1] = (f16)a0.y; ha[2] = (f16)a0.z; ha[3] = (f16)a0.w;
        ha[4] = (f16)a1.x; ha[5] = (f16)a1.y; ha[6] = (f16)a1.z; ha[7] = (f16)a1.w;
        hb[0] = (f16)a2.x; hb[1] = (f16)a2.y; hb[2] = (f16)a2.z; hb[3] = (f16)a2.w;
        hb[4] = (f16)a3.x; hb[5] = (f16)a3.y; hb[6] = (f16)a3.z; hb[7] = (f16)a3.w;
        *(f16x8*)(As + srow * 32 + ((sc0    ) ^ swz) * 8) = ha;
        *(f16x8*)(As + srow * 32 + ((sc0 + 1) ^ swz) * 8) = hb;
        // stage B (already f16, rows = output cols)
        f16x8 b0 = *(const f16x8*)(brow + k0);
        f16x8 b1 = *(const f16x8*)(brow + k0 + 8);
        *(f16x8*)(Bs + srow * 32 + ((sc0    ) ^ swz) * 8) = b0;
        *(f16x8*)(Bs + srow * 32 + ((sc0 + 1) ^ swz) * 8) = b1;
        __syncthreads();

        f16x8 af[4], bf[4];
        #pragma unroll
        for (int fm = 0; fm < 4; fm++) {
            int r = wm * 64 + fm * 16 + lr;
            af[fm] = *(const f16x8*)(As + r * 32 + (lh ^ ((r >> 1) & 3)) * 8);
        }
        #pragma unroll
        for (int fn = 0; fn < 4; fn++) {
            int r = wn * 64 + fn * 16 + lr;
            bf[fn] = *(const f16x8*)(Bs + r * 32 + (lh ^ ((r >> 1) & 3)) * 8);
        }
        #pragma unroll
        for (int fm = 0; fm < 4; fm++)
            #pragma unroll
            for (int fn = 0; fn < 4; fn++)
                acc[fm][fn] = MFMA16(af[fm], bf[fn], acc[fm][fn]);
    }

    __syncthreads();
    // epilogue: +bias, f32->f16, LDS transpose for coalesced stores
    f16* Os = smem;                        // [128][128]
    #pragma unroll
    for (int fn = 0; fn < 4; fn++) {
        float bv = bias[n0 + wn * 64 + fn * 16 + lr];
        #pragma unroll
        for (int fm = 0; fm < 4; fm++) {
            #pragma unroll
            for (int r = 0; r < 4; r++) {
                int row = wm * 64 + fm * 16 + lh * 4 + r;   // C/D: row=(lane>>4)*4+reg
                int col = wn * 64 + fn * 16 + lr;           //      col=lane&15
                Os[row * 128 + col] = (f16)(acc[fm][fn][r] + bv);
            }
        }
    }
    __syncthreads();
    const int orow = tid >> 1;
    const int ocol = (tid & 1) * 64;
    f16* dst = xg + (m0 + orow) * 2048 + n0 + ocol;
    const f16* srcp = Os + orow * 128 + ocol;
    #pragma unroll
    for (int j = 0; j < 8; j++)
        *(uint4*)(dst + j * 8) = *(const uint4*)(srcp + j * 8);
}

// ---------------------------------------------------------------- recurrence
// 128 wgs x 256 thr. wg = (group g = bid>>4: batches g*16..+15, slice s = bid&15:
// hidden units s*32..+31 i.e. gate cols {w*512 + s*32 + u}). Wave w handles gate w.
// Wh slice lives in registers (f16x8 breg[2][16] = 128 VGPR). h via global dbuf.
__global__ __launch_bounds__(256, 1) void lstm_rec(
    const f16* __restrict__ whT, const f16* __restrict__ xg,
    f16* __restrict__ hbuf, float* __restrict__ cst,
    float* __restrict__ out, unsigned* __restrict__ cnt,
    int t0, int tcLog)
{
    __shared__ float gl[2048];             // [gate][16 b][32 u] f32, 8 KB
    const int tid = threadIdx.x;
    const int lane = tid & 63, w = tid >> 6;
    const int lr = lane & 15, lh = lane >> 4;
    const int g = blockIdx.x >> 4, s = blockIdx.x & 15;
    const int Tc = 1 << tcLog;

    // load Wh B-fragments into registers (one-time)
    f16x8 breg[2][16];
    #pragma unroll
    for (int fn = 0; fn < 2; fn++) {
        const f16* wp = whT + (long)(w * 512 + s * 32 + fn * 16 + lr) * 512 + lh * 8;
        #pragma unroll
        for (int ks = 0; ks < 16; ks++)
            breg[fn][ks] = *(const f16x8*)(wp + ks * 32);
    }

    // pointwise ownership: thread -> (batch pb, units pu, pu+1); c in registers
    const int pb = tid >> 4;
    const int pu = (tid & 15) * 2;
    const int bg = g * 16 + pb;
    const int hcol = s * 32 + pu;
    float2 cc = *(const float2*)(cst + bg * 512 + hcol);

    const long aoff = (long)(g * 16 + lr) * 512 + lh * 8;  // A-frag: m=batch-local=lr
    unsigned* cptr = cnt + g * 64;

    for (int t = 0; t < Tc; t++) {
        const int tt = t0 + t;
        // prefetch xg for this step (hides HBM latency under MFMA)
        const f16* xr = xg + ((long)(bg << tcLog) + t) * 2048 + hcol;
        f16x2 xv0 = *(const f16x2*)(xr);
        f16x2 xv1 = *(const f16x2*)(xr + 512);
        f16x2 xv2 = *(const f16x2*)(xr + 1024);
        f16x2 xv3 = *(const f16x2*)(xr + 1536);

        const f16* hr = hbuf + (tt & 1) * 65536 + aoff;
        f32x4 acc0 = {0.f, 0.f, 0.f, 0.f}, acc1 = {0.f, 0.f, 0.f, 0.f};
        #pragma unroll
        for (int ks = 0; ks < 16; ks++) {
            f16x8 a = *(const f16x8*)(hr + ks * 32);
            acc0 = MFMA16(a, breg[0][ks], acc0);
            acc1 = MFMA16(a, breg[1][ks], acc1);
        }
        #pragma unroll
        for (int r = 0; r < 4; r++) {
            gl[w * 512 + (lh * 4 + r) * 32 + lr] = acc0[r];
            gl[w * 512 + (lh * 4 + r) * 32 + 16 + lr] = acc1[r];
        }
        __syncthreads();

        float2 gi = *(const float2*)(gl + 0 * 512 + pb * 32 + pu);
        float2 gf = *(const float2*)(gl + 1 * 512 + pb * 32 + pu);
        float2 gg = *(const float2*)(gl + 2 * 512 + pb * 32 + pu);
        float2 go = *(const float2*)(gl + 3 * 512 + pb * 32 + pu);
        float i0 = sigf(gi.x + (float)xv0[0]);
        float i1 = sigf(gi.y + (float)xv0[1]);
        float f0 = sigf(gf.x + (float)xv1[0]);
        float f1 = sigf(gf.y + (float)xv1[1]);
        float g0 = tanh_fast(gg.x + (float)xv2[0]);
        float g1 = tanh_fast(gg.y + (float)xv2[1]);
        float o0 = sigf(go.x + (float)xv3[0]);
        float o1 = sigf(go.y + (float)xv3[1]);
        cc.x = f0 * cc.x + i0 * g0;
        cc.y = f1 * cc.y + i1 * g1;
        float h0 = o0 * tanh_fast(cc.x);
        float h1 = o1 * tanh_fast(cc.y);
        f16x2 hv; hv[0] = (f16)h0; hv[1] = (f16)h1;
        *(f16x2*)(hbuf + ((tt + 1) & 1) * 65536 + bg * 512 + hcol) = hv;
        if (tt == 1023) *(float2*)(out + bg * 512 + hcol) = make_float2(h0, h1);

        // group barrier: release own writes, arrive, spin, acquire
        __builtin_amdgcn_fence(__ATOMIC_RELEASE, "agent");
        __syncthreads();
        if (tid == 0) {
            __hip_atomic_fetch_add(cptr, 1u, __ATOMIC_RELAXED, __HIP_MEMORY_SCOPE_AGENT);
            unsigned target = (unsigned)(tt + 1) * 16u;
            while (__hip_atomic_load(cptr, __ATOMIC_RELAXED, __HIP_MEMORY_SCOPE_AGENT) < target) {}
        }
        __syncthreads();
        __builtin_amdgcn_fence(__ATOMIC_ACQUIRE, "agent");
    }
    *(float2*)(cst + bg * 512 + hcol) = cc;
}

// ---------------------------------------------------------------- host
extern "C" void kernel_launch(void* const* d_in, const int* in_sizes, int n_in,
                              void* d_out, int out_size, void* d_ws, size_t ws_size,
                              hipStream_t stream)
{
    const float* x    = (const float*)d_in[0];
    const float* Wx   = (const float*)d_in[1];
    const float* Wh   = (const float*)d_in[2];
    const float* bias = (const float*)d_in[3];
    float* out = (float*)d_out;
    char* ws = (char*)d_ws;

    f16*      wxT  = (f16*)(ws);                  // 2 MiB
    f16*      whT  = (f16*)(ws + 2097152);        // 2 MiB
    f16*      hbuf = (f16*)(ws + 4194304);        // 256 KiB (double buffer)
    float*    cst  = (float*)(ws + 4456448);      // 256 KiB
    unsigned* cnt  = (unsigned*)(ws + 4718592);   // 2 KiB
    f16*      xgb  = (f16*)(ws + 4720640);        // Tc*128*2048*2 bytes

    int tcLog = 10;
    while (tcLog > 0 && 4720640ull + (524288ull << tcLog) > ws_size) tcLog--;
    const int nch = 1024 >> tcLog;

    prep_kernel<<<4096, 256, 0, stream>>>(Wx, Wh, wxT, whT, hbuf, cst, cnt);

    for (int c = 0; c < nch; c++) {
        int t0 = c << tcLog;
        dim3 gA(16, 1u << tcLog);
        gemm_xg<<<gA, 256, 0, stream>>>(x, wxT, bias, xgb, t0, tcLog);

        const f16* whT_a = whT; const f16* xg_a = xgb; f16* hbuf_a = hbuf;
        float* cst_a = cst; float* out_a = out; unsigned* cnt_a = cnt;
        int t0_a = t0, tcl_a = tcLog;
        void* args[8] = { &whT_a, &xg_a, &hbuf_a, &cst_a, &out_a, &cnt_a, &t0_a, &tcl_a };
        if (hipLaunchCooperativeKernel((const void*)lstm_rec, dim3(128), dim3(256),
                                       args, 0, stream) != hipSuccess) {
            // fallback: 128 wgs on a 256-CU chip are co-resident under any scheduler
            lstm_rec<<<dim3(128), dim3(256), 0, stream>>>(whT, xgb, hbuf, cst, out, cnt, t0, tcLog);
        }
    }
}

// Round 3
// 4325.523 us; speedup vs baseline: 3.5441x; 3.5441x over previous
//
#include <hip/hip_runtime.h>

// LSTM: B=128, T=1024, D=512, H=512, gates 4H=2048.
// in: x (B,T,D) f32 | Wx (512,2048) f32 | Wh (512,2048) f32 | b (2048) f32
// out: final h (128,512) f32
//
//  prep:    Wx,Wh -> f16 transposed [2048][512]; zero h/c/sync region
//  gemm_xg: xg = x@Wx + b  (f16, chunked over T by ws_size)
//  lstm_rec: 128 WGs = 8 groups (16 batches) x 16 hidden-slice WGs (blockIdx
//            grouping — round-1-proven co-residency). h exchange via sc0 sc1
//            (mem-side coherent Infinity Cache) loads/stores; group barrier via
//            device-scope atomics. NO cache-flush fences anywhere in the loop.

typedef _Float16 f16;
typedef _Float16 f16x2 __attribute__((ext_vector_type(2)));
typedef _Float16 f16x8 __attribute__((ext_vector_type(8)));
typedef float f32x4 __attribute__((ext_vector_type(4)));

#define MFMA16(a, b, c) __builtin_amdgcn_mfma_f32_16x16x32_f16(a, b, c, 0, 0, 0)

__device__ __forceinline__ float sigf(float x) { return 1.0f / (1.0f + __expf(-x)); }
__device__ __forceinline__ float tanh_fast(float x) { return 1.0f - 2.0f / (__expf(2.0f * x) + 1.0f); }

// ws layout (bytes)
#define OFF_WXT   0ull
#define OFF_WHT   2097152ull
#define OFF_HBUF  4194304ull   // [2][128][512] f16 = 256 KiB
#define OFF_CST   4456448ull   // [128][512] f32   = 256 KiB
#define OFF_SYNC  4718592ull   // 64 KiB sync region (u32[16384])
#define OFF_XG    4784128ull

// ---------------------------------------------------------------- prep
__global__ __launch_bounds__(256) void prep_kernel(
    const float* __restrict__ Wx, const float* __restrict__ Wh,
    f16* __restrict__ wxT, f16* __restrict__ whT,
    f16* __restrict__ hbuf, float* __restrict__ cst, unsigned* __restrict__ syncb)
{
    unsigned i = blockIdx.x * 256u + threadIdx.x;
    if (i < 1048576u) {                    // 2048*512 transpose, W[d][g] -> WT[g][d]
        unsigned g = i >> 9, d = i & 511u;
        wxT[i] = (f16)Wx[d * 2048u + g];
        whT[i] = (f16)Wh[d * 2048u + g];
    }
    if (i < 65536u) {                      // zero h double-buffer + c state
        ((unsigned*)hbuf)[i] = 0u;
        cst[i] = 0.0f;
    }
    if (i < 16384u) syncb[i] = 0u;         // barrier counters
}

// ---------------------------------------------------------------- xg GEMM
// M = 128*Tc (row = b*Tc + t_local), N = 2048, K = 512. 128x128 tile, 4 waves.
__global__ __launch_bounds__(256) void gemm_xg(
    const float* __restrict__ x, const f16* __restrict__ wxT,
    const float* __restrict__ bias, f16* __restrict__ xg,
    int t0, int tcLog)
{
    __shared__ f16 smem[16384];            // A[128][32] | B[128][32], reused as Os[128][128]
    f16* As = smem;
    f16* Bs = smem + 4096;

    const int tid = threadIdx.x;
    const int lane = tid & 63, wid = tid >> 6;
    const int wm = wid >> 1, wn = wid & 1;
    const int lr = lane & 15, lh = lane >> 4;
    const int n0 = blockIdx.x * 128;
    const long m0 = (long)blockIdx.y * 128;

    const int srow = tid >> 1;
    const int sc0_ = (tid & 1) * 2;
    const int swz = (srow >> 1) & 3;

    const long mg = m0 + srow;
    const long bb = mg >> tcLog;
    const long tl = mg & ((1L << tcLog) - 1);
    const float* xrow = x + ((bb * 1024 + t0 + tl) * 512 + sc0_ * 8);
    const f16* brow = wxT + ((long)(n0 + srow) * 512 + sc0_ * 8);

    f32x4 acc[4][4] = {};

    for (int k0 = 0; k0 < 512; k0 += 32) {
        __syncthreads();
        float4 a0 = *(const float4*)(xrow + k0);
        float4 a1 = *(const float4*)(xrow + k0 + 4);
        float4 a2 = *(const float4*)(xrow + k0 + 8);
        float4 a3 = *(const float4*)(xrow + k0 + 12);
        f16x8 ha, hb;
        ha[0] = (f16)a0.x; ha[1] = (f16)a0.y; ha[2] = (f16)a0.z; ha[3] = (f16)a0.w;
        ha[4] = (f16)a1.x; ha[5] = (f16)a1.y; ha[6] = (f16)a1.z; ha[7] = (f16)a1.w;
        hb[0] = (f16)a2.x; hb[1] = (f16)a2.y; hb[2] = (f16)a2.z; hb[3] = (f16)a2.w;
        hb[4] = (f16)a3.x; hb[5] = (f16)a3.y; hb[6] = (f16)a3.z; hb[7] = (f16)a3.w;
        *(f16x8*)(As + srow * 32 + ((sc0_    ) ^ swz) * 8) = ha;
        *(f16x8*)(As + srow * 32 + ((sc0_ + 1) ^ swz) * 8) = hb;
        f16x8 b0 = *(const f16x8*)(brow + k0);
        f16x8 b1 = *(const f16x8*)(brow + k0 + 8);
        *(f16x8*)(Bs + srow * 32 + ((sc0_    ) ^ swz) * 8) = b0;
        *(f16x8*)(Bs + srow * 32 + ((sc0_ + 1) ^ swz) * 8) = b1;
        __syncthreads();

        f16x8 af[4], bf[4];
        #pragma unroll
        for (int fm = 0; fm < 4; fm++) {
            int r = wm * 64 + fm * 16 + lr;
            af[fm] = *(const f16x8*)(As + r * 32 + (lh ^ ((r >> 1) & 3)) * 8);
        }
        #pragma unroll
        for (int fn = 0; fn < 4; fn++) {
            int r = wn * 64 + fn * 16 + lr;
            bf[fn] = *(const f16x8*)(Bs + r * 32 + (lh ^ ((r >> 1) & 3)) * 8);
        }
        #pragma unroll
        for (int fm = 0; fm < 4; fm++)
            #pragma unroll
            for (int fn = 0; fn < 4; fn++)
                acc[fm][fn] = MFMA16(af[fm], bf[fn], acc[fm][fn]);
    }

    __syncthreads();
    f16* Os = smem;                        // [128][128]
    #pragma unroll
    for (int fn = 0; fn < 4; fn++) {
        float bv = bias[n0 + wn * 64 + fn * 16 + lr];
        #pragma unroll
        for (int fm = 0; fm < 4; fm++) {
            #pragma unroll
            for (int r = 0; r < 4; r++) {
                int row = wm * 64 + fm * 16 + lh * 4 + r;
                int col = wn * 64 + fn * 16 + lr;
                Os[row * 128 + col] = (f16)(acc[fm][fn][r] + bv);
            }
        }
    }
    __syncthreads();
    const int orow = tid >> 1;
    const int ocol = (tid & 1) * 64;
    f16* dst = xg + (m0 + orow) * 2048 + n0 + ocol;
    const f16* srcp = Os + orow * 128 + ocol;
    #pragma unroll
    for (int j = 0; j < 8; j++)
        *(uint4*)(dst + j * 8) = *(const uint4*)(srcp + j * 8);
}

// ---------------------------------------------------------------- recurrence
// 128 WGs x 256 thr. g = bid>>4 (batches g*16..+15), s = bid&15 (hidden units
// s*32..+31, i.e. gate cols {w*512 + s*32 + u}). Wave w computes gate w.
// Wh slice in registers. h via mem-side-coherent (sc0 sc1) global double buffer.
__global__ __launch_bounds__(256, 1) void lstm_rec(
    const f16* __restrict__ whT, const f16* __restrict__ xg,
    f16* __restrict__ hbuf, float* __restrict__ cst,
    float* __restrict__ out, unsigned* __restrict__ syncb,
    int t0, int tcLog)
{
    __shared__ float gl[2048];             // [gate][16 b][32 u] f32, 8 KB
    const int tid = threadIdx.x;
    const int lane = tid & 63, w = tid >> 6;
    const int lr = lane & 15, lh = lane >> 4;
    const int g = blockIdx.x >> 4, s = blockIdx.x & 15;
    const int Tc = 1 << tcLog;

    // Wh slice -> registers (one-time)
    f16x8 breg[2][16];
    #pragma unroll
    for (int fn = 0; fn < 2; fn++) {
        const f16* wp = whT + (long)(w * 512 + s * 32 + fn * 16 + lr) * 512 + lh * 8;
        #pragma unroll
        for (int ks = 0; ks < 16; ks++)
            breg[fn][ks] = *(const f16x8*)(wp + ks * 32);
    }

    const int pb = tid >> 4;
    const int pu = (tid & 15) * 2;
    const int bg = g * 16 + pb;
    const int hcol = s * 32 + pu;
    float2 cc = *(const float2*)(cst + bg * 512 + hcol);

    const long aoff = (long)(g * 16 + lr) * 512 + lh * 8;   // A-frag: m=batch-local=lr
    unsigned* cptr = syncb + g * 64;
    const f16* xbase = xg + ((long)(bg << tcLog)) * 2048 + hcol;

    // preload xg for t=0 (plain cached loads)
    f16x2 xv0 = *(const f16x2*)(xbase);
    f16x2 xv1 = *(const f16x2*)(xbase + 512);
    f16x2 xv2 = *(const f16x2*)(xbase + 1024);
    f16x2 xv3 = *(const f16x2*)(xbase + 1536);

    for (int t = 0; t < Tc; t++) {
        const int tt = t0 + t;

        // h_t A-fragments: mem-side coherent loads (bypass L1+L2)
        const f16* hr = hbuf + (tt & 1) * 65536 + aoff;
        f16x8 a[16];
        #pragma unroll
        for (int ks = 0; ks < 16; ks++)
            asm volatile("global_load_dwordx4 %0, %1, off sc0 sc1"
                         : "=v"(a[ks]) : "v"(hr + ks * 32) : "memory");
        asm volatile("s_waitcnt vmcnt(0)" ::: "memory");
        __builtin_amdgcn_sched_barrier(0);                  // no MFMA hoist above waitcnt

        f32x4 acc0 = {0.f, 0.f, 0.f, 0.f}, acc1 = {0.f, 0.f, 0.f, 0.f};
        #pragma unroll
        for (int ks = 0; ks < 16; ks++) {
            acc0 = MFMA16(a[ks], breg[0][ks], acc0);
            acc1 = MFMA16(a[ks], breg[1][ks], acc1);
        }
        #pragma unroll
        for (int r = 0; r < 4; r++) {
            gl[w * 512 + (lh * 4 + r) * 32 + lr] = acc0[r];
            gl[w * 512 + (lh * 4 + r) * 32 + 16 + lr] = acc1[r];
        }
        __syncthreads();

        float2 gi = *(const float2*)(gl + 0 * 512 + pb * 32 + pu);
        float2 gf = *(const float2*)(gl + 1 * 512 + pb * 32 + pu);
        float2 gg = *(const float2*)(gl + 2 * 512 + pb * 32 + pu);
        float2 go = *(const float2*)(gl + 3 * 512 + pb * 32 + pu);
        float i0 = sigf(gi.x + (float)xv0[0]);
        float i1 = sigf(gi.y + (float)xv0[1]);
        float f0 = sigf(gf.x + (float)xv1[0]);
        float f1 = sigf(gf.y + (float)xv1[1]);
        float g0 = tanh_fast(gg.x + (float)xv2[0]);
        float g1 = tanh_fast(gg.y + (float)xv2[1]);
        float o0 = sigf(go.x + (float)xv3[0]);
        float o1 = sigf(go.y + (float)xv3[1]);
        cc.x = f0 * cc.x + i0 * g0;
        cc.y = f1 * cc.y + i1 * g1;
        float h0 = o0 * tanh_fast(cc.x);
        float h1 = o1 * tanh_fast(cc.y);
        f16x2 hv; hv[0] = (f16)h0; hv[1] = (f16)h1;

        // h_{t+1} store: mem-side coherent (write-through to Infinity Cache)
        {
            f16* hdst = hbuf + ((tt + 1) & 1) * 65536 + bg * 512 + hcol;
            union { f16x2 h; unsigned u; } cv; cv.h = hv;
            asm volatile("global_store_dword %0, %1, off sc0 sc1"
                         :: "v"(hdst), "v"(cv.u) : "memory");
        }
        if (tt == 1023) *(float2*)(out + bg * 512 + hcol) = make_float2(h0, h1);

        // prefetch next step's xg (plain, cached) — latency hides under barrier
        if (t + 1 < Tc) {
            const f16* xr = xbase + (long)(t + 1) * 2048;
            xv0 = *(const f16x2*)(xr);
            xv1 = *(const f16x2*)(xr + 512);
            xv2 = *(const f16x2*)(xr + 1024);
            xv3 = *(const f16x2*)(xr + 1536);
        }

        // group barrier: __syncthreads drains (vmcnt0) the sc1 store to the
        // coherent point in every wave, then one device-scope atomic per WG.
        __syncthreads();
        if (tid == 0) {
            const unsigned target = (unsigned)(tt + 1) * 16u;
            __hip_atomic_fetch_add(cptr, 1u, __ATOMIC_RELAXED, __HIP_MEMORY_SCOPE_AGENT);
            int guard = 0;                 // bounded spin: never hang the harness
            while (__hip_atomic_load(cptr, __ATOMIC_RELAXED, __HIP_MEMORY_SCOPE_AGENT) < target
                   && guard < 20000) guard++;
        }
        __syncthreads();
    }
    *(float2*)(cst + bg * 512 + hcol) = cc;
}

// ---------------------------------------------------------------- host
extern "C" void kernel_launch(void* const* d_in, const int* in_sizes, int n_in,
                              void* d_out, int out_size, void* d_ws, size_t ws_size,
                              hipStream_t stream)
{
    const float* x    = (const float*)d_in[0];
    const float* Wx   = (const float*)d_in[1];
    const float* Wh   = (const float*)d_in[2];
    const float* bias = (const float*)d_in[3];
    float* out = (float*)d_out;
    char* ws = (char*)d_ws;

    f16*      wxT   = (f16*)(ws + OFF_WXT);
    f16*      whT   = (f16*)(ws + OFF_WHT);
    f16*      hbuf  = (f16*)(ws + OFF_HBUF);
    float*    cst   = (float*)(ws + OFF_CST);
    unsigned* syncb = (unsigned*)(ws + OFF_SYNC);
    f16*      xgb   = (f16*)(ws + OFF_XG);

    int tcLog = 10;
    while (tcLog > 0 && OFF_XG + (524288ull << tcLog) > ws_size) tcLog--;
    const int nch = 1024 >> tcLog;

    prep_kernel<<<4096, 256, 0, stream>>>(Wx, Wh, wxT, whT, hbuf, cst, syncb);

    for (int c = 0; c < nch; c++) {
        int t0 = c << tcLog;
        dim3 gA(16, 1u << tcLog);
        gemm_xg<<<gA, 256, 0, stream>>>(x, wxT, bias, xgb, t0, tcLog);

        const f16* whT_a = whT; const f16* xg_a = xgb; f16* hbuf_a = hbuf;
        float* cst_a = cst; float* out_a = out; unsigned* syncb_a = syncb;
        int t0_a = t0, tcl_a = tcLog;
        void* args[8] = { &whT_a, &xg_a, &hbuf_a, &cst_a, &out_a, &syncb_a, &t0_a, &tcl_a };
        if (hipLaunchCooperativeKernel((const void*)lstm_rec, dim3(128), dim3(256),
                                       args, 0, stream) != hipSuccess) {
            // 128 WGs (256 thr, 8KB LDS) on 256 CUs are co-resident (round-1-proven)
            lstm_rec<<<dim3(128), dim3(256), 0, stream>>>(whT, xgb, hbuf, cst, out, syncb, t0, tcLog);
        }
    }
}